// Round 22
// baseline (2575.769 us; speedup 1.0000x reference)
//
#include <hip/hip_runtime.h>
#include <stdint.h>

#define NB 256      // batch
#define TSEQ 1024   // sequence length
#define TT_MAX 64

// v10.3: 512 threads, K split between lane pairs. Per HALF-row (64 pairs = 16 quads):
// quads 0..2 reg, 3..8 LDS, 9..15 streamed as 7 chunks (1 quad x 3 rows), depth-3.
#define REG_P 12    // pairs in registers (3*12 = 36 VGPRs)
#define LDS_P 24    // pairs in LDS (3*24 = 72 u32/thread)
#define LDSTR 76    // u32 stride of per-thread LDS slice (proven 0-conflict R20/R21)

typedef _Float16 f16;
typedef _Float16 h2 __attribute__((ext_vector_type(2)));

static __device__ __forceinline__ uint32_t pkh2(float a, float b) {
  h2 v; v[0] = (f16)a; v[1] = (f16)b;
  return __builtin_bit_cast(uint32_t, v);
}

#if __has_builtin(__builtin_amdgcn_fdot2)
static __device__ __forceinline__ float dot2u(uint32_t w, uint32_t h, float c) {
  return __builtin_amdgcn_fdot2(__builtin_bit_cast(h2, w), __builtin_bit_cast(h2, h), c, false);
}
#else
static __device__ __forceinline__ float dot2u(uint32_t w, uint32_t h, float c) {
  h2 a = __builtin_bit_cast(h2, w), b = __builtin_bit_cast(h2, h);
  return c + (float)a[0] * (float)b[0] + (float)a[1] * (float)b[1];
}
#endif

#if __has_builtin(__builtin_amdgcn_rcpf)
#define RCPF(x) __builtin_amdgcn_rcpf(x)
#else
#define RCPF(x) (1.0f / (x))
#endif

static __device__ __forceinline__ float sigm(float x) {
  return RCPF(1.0f + exp2f(-1.44269504f * x));
}
static __device__ __forceinline__ float tanh_f(float x) {
  return 1.0f - 2.0f * RCPF(1.0f + exp2f(2.88539008f * x));
}

// ---------------------------------------------------------------------------
// One-time weight pack (f16), 512-thread consumer layout.
// Thread t: row r=t>>1, k-half q=t&1 (f16-pairs [64q, 64q+64) of each row).
//  whr : [(rr*3+cj)*512 + t] uint4, quads 0..2 (pairs [0,12))
//  whl : [t*LDSTR + rr*24 + p],     pairs [12,36) (quads 3..8)
//  whs : [(c*3+rr)*512 + t] uint4 — chunk c = quad 9+c (c=0..6), row rr
//  whz : [(rr*2+cj)*512 + t] uint4, z-pairs [8q, 8q+8)
//  wep : [p4*512 + t] uint4 — enc row e=t&63, k-slice s=t>>6 (16 pairs)
// ---------------------------------------------------------------------------
__global__ __launch_bounds__(512) void vrnn_pack(
    const float* __restrict__ W_hh, const float* __restrict__ W_ih,
    const float* __restrict__ emW, const float* __restrict__ esW,
    uint32_t* __restrict__ whr, uint32_t* __restrict__ whl,
    uint32_t* __restrict__ whs, uint32_t* __restrict__ whz,
    uint32_t* __restrict__ wep)
{
  const int t = threadIdx.x;
  const int r = t >> 1, q = t & 1;
  for (int rr = 0; rr < 3; ++rr) {
    const float* R = W_hh + (size_t)(r + rr * 256) * 256 + q * 128;
    for (int cj = 0; cj < 3; ++cj)
      for (int i = 0; i < 4; ++i) {
        int p = cj * 4 + i;
        whr[(((size_t)rr * 3 + cj) * 512 + t) * 4 + i] = pkh2(R[2 * p], R[2 * p + 1]);
      }
    for (int p = 0; p < LDS_P; ++p)
      whl[(size_t)t * LDSTR + rr * LDS_P + p] = pkh2(R[2 * (p + REG_P)], R[2 * (p + REG_P) + 1]);
    for (int c = 0; c < 7; ++c)
      for (int i = 0; i < 4; ++i) {
        int p = (9 + c) * 4 + i;   // pairs [36,64)
        whs[(((size_t)c * 3 + rr) * 512 + t) * 4 + i] = pkh2(R[2 * p], R[2 * p + 1]);
      }
    const float* Z = W_ih + (size_t)(r + rr * 256) * 96 + 64 + q * 16;
    for (int cj = 0; cj < 2; ++cj)
      for (int i = 0; i < 4; ++i) {
        int p = cj * 4 + i;
        whz[(((size_t)rr * 2 + cj) * 512 + t) * 4 + i] = pkh2(Z[2 * p], Z[2 * p + 1]);
      }
  }
  {
    const int e = t & 63, s = t >> 6;
    const float* esrc = (e < 32) ? (emW + (size_t)e * 320 + 64)
                                 : (esW + (size_t)(e - 32) * 320 + 64);
    for (int p4 = 0; p4 < 4; ++p4)
      for (int i = 0; i < 4; ++i) {
        int pc = s * 16 + p4 * 4 + i;
        wep[((size_t)p4 * 512 + t) * 4 + i] = pkh2(esrc[2 * pc], esrc[2 * pc + 1]);
      }
  }
}

// ---------------------------------------------------------------------------
// Precompute kernel (unchanged): gi_x'[t][b][768], zx'[t][b][64]
// ---------------------------------------------------------------------------
__global__ __launch_bounds__(256, 2) void vrnn_pre(
    const float* __restrict__ x, const float* __restrict__ W_ih,
    const float* __restrict__ b_ih, const float* __restrict__ b_hh,
    const float* __restrict__ emW, const float* __restrict__ emb,
    const float* __restrict__ esW, const float* __restrict__ esb,
    f16* __restrict__ gix, f16* __restrict__ zx,
    int chunk_t0, int TT, int nTT)
{
  const int tid = threadIdx.x;
  const int b  = blockIdx.x / nTT;
  const int tt = blockIdx.x % nTT;
  const int tloc0 = tt * TT;

  uint32_t wx[3][32];
  float bias[3];
  #pragma unroll
  for (int rr = 0; rr < 3; ++rr) {
    int j = tid + rr * 256;
    const float4* wr = (const float4*)(W_ih + (size_t)j * 96);
    #pragma unroll
    for (int p4 = 0; p4 < 16; ++p4) {
      float4 v = wr[p4];
      wx[rr][2 * p4]     = pkh2(v.x, v.y);
      wx[rr][2 * p4 + 1] = pkh2(v.z, v.w);
    }
    bias[rr] = b_ih[j] + (rr < 2 ? b_hh[j] : 0.0f);  // fold b_hh into r,z rows only
  }
  uint32_t we[32]; float ebias = 0.0f;
  if (tid < 64) {
    const float* src = (tid < 32) ? (emW + (size_t)tid * 320)
                                  : (esW + (size_t)(tid - 32) * 320);
    #pragma unroll
    for (int p = 0; p < 32; ++p) we[p] = pkh2(src[2 * p], src[2 * p + 1]);
    ebias = (tid < 32) ? emb[tid] : esb[tid - 32];
  }

  __shared__ uint32_t xs[TT_MAX * 32];
  for (int idx = tid; idx < TT * 32; idx += 256) {
    int tl = idx >> 5, pk = idx & 31;
    size_t base = ((size_t)b * TSEQ + (chunk_t0 + tloc0 + tl)) * 64 + 2 * pk;
    xs[idx] = pkh2(x[base], x[base + 1]);
  }
  __syncthreads();

  for (int tl = 0; tl < TT; ++tl) {
    float a0 = bias[0], a1 = bias[1], a2 = bias[2];
    #pragma unroll
    for (int p = 0; p < 32; ++p) {
      uint32_t u = xs[tl * 32 + p];
      a0 = dot2u(wx[0][p], u, a0);
      a1 = dot2u(wx[1][p], u, a1);
      a2 = dot2u(wx[2][p], u, a2);
    }
    size_t ob = (size_t)(tloc0 + tl) * NB + b;
    f16* g = gix + ob * 768;
    g[tid] = (f16)a0; g[tid + 256] = (f16)a1; g[tid + 512] = (f16)a2;
    if (tid < 64) {
      float a3 = ebias;
      #pragma unroll
      for (int p = 0; p < 32; ++p) a3 = dot2u(we[p], xs[tl * 32 + p], a3);
      zx[ob * 64 + tid] = (f16)a3;
    }
  }
}

// consume chunk (3 weight uint4, 1 h-quad): 12 dots
#define CONS(B0, B1, B2, HQI) { \
  uint4 hq = hu4[HQI]; \
  g0 = dot2u(B0.x, hq.x, g0); g0 = dot2u(B0.y, hq.y, g0); \
  g0 = dot2u(B0.z, hq.z, g0); g0 = dot2u(B0.w, hq.w, g0); \
  g1 = dot2u(B1.x, hq.x, g1); g1 = dot2u(B1.y, hq.y, g1); \
  g1 = dot2u(B1.z, hq.z, g1); g1 = dot2u(B1.w, hq.w, g1); \
  g2 = dot2u(B2.x, hq.x, g2); g2 = dot2u(B2.y, hq.y, g2); \
  g2 = dot2u(B2.z, hq.z, g2); g2 = dot2u(B2.w, hq.w, g2); }

// issue chunk C into buffers
#define ISS(B0, B1, B2, C) { \
  B0 = whs4[((C) * 3 + 0) * 512 + t]; \
  B1 = whs4[((C) * 3 + 1) * 512 + t]; \
  B2 = whs4[((C) * 3 + 2) * 512 + t]; \
  __builtin_amdgcn_sched_barrier(0); }

// LDS weight quad G (h quad bq+3+G): 12 dots
#define LQ(G) { \
  uint4 u4 = hu4[bq + 3 + (G)]; \
  uint4 w0 = *(const uint4*)(myl + 0 * LDS_P + 4 * (G)); \
  uint4 w1 = *(const uint4*)(myl + 1 * LDS_P + 4 * (G)); \
  uint4 w2 = *(const uint4*)(myl + 2 * LDS_P + 4 * (G)); \
  g0 = dot2u(w0.x, u4.x, g0); g1 = dot2u(w1.x, u4.x, g1); g2 = dot2u(w2.x, u4.x, g2); \
  g0 = dot2u(w0.y, u4.y, g0); g1 = dot2u(w1.y, u4.y, g1); g2 = dot2u(w2.y, u4.y, g2); \
  g0 = dot2u(w0.z, u4.z, g0); g1 = dot2u(w1.z, u4.z, g1); g2 = dot2u(w2.z, u4.z, g2); \
  g0 = dot2u(w0.w, u4.w, g0); g1 = dot2u(w1.w, u4.w, g1); g2 = dot2u(w2.w, u4.w, g2); }

// ---------------------------------------------------------------------------
// Recurrent kernel v10.3: v10.2 + depth-3 stream pipeline.
// R21 post-mortem: 1.13ms, VALU 48.5%; residual stall = L2 latency at the 3
// consume points (issue->consume gap 150-200cyc ~ L2 latency). Split stream
// into 7 chunks of 1 quad x 3 rows (12 regs each); 3 rotating buffers
// (sa/sb/sc) = depth-3: every chunk issued ~60 dots (~240+ cyc wall) before
// consumption. REG_P 16->12 pays the extra buffer (pinned 76 + sbuf 36 = 112,
// same budget as R21's proven VGPR=120).
// ---------------------------------------------------------------------------
__global__ __launch_bounds__(512) void vrnn_rec(
    const f16* __restrict__ gix, const f16* __restrict__ zx,
    const float* __restrict__ eps,
    const uint32_t* __restrict__ whr, const uint32_t* __restrict__ whl_g,
    const uint32_t* __restrict__ whs, const uint32_t* __restrict__ whz,
    const uint32_t* __restrict__ wep_g,
    const float* __restrict__ b_hh,
    float* __restrict__ hws, float* __restrict__ out,
    int t0, int Tlen, int first, int last)
{
  const int t = threadIdx.x;
  const int b = blockIdx.x;
  const int r = t >> 1, q = t & 1;

  // ---- pinned register weights ----
  uint32_t wrg[3][REG_P];              // 36
  {
    const uint4* w4 = (const uint4*)whr;
    #pragma unroll
    for (int c = 0; c < 9; ++c) {
      uint4 v = w4[c * 512 + t];
      int rr = c / 3, p4 = c % 3;
      wrg[rr][4 * p4] = v.x; wrg[rr][4 * p4 + 1] = v.y;
      wrg[rr][4 * p4 + 2] = v.z; wrg[rr][4 * p4 + 3] = v.w;
    }
  }
  uint32_t wz[3][8];                   // 24
  {
    const uint4* w4 = (const uint4*)whz;
    #pragma unroll
    for (int c = 0; c < 6; ++c) {
      uint4 v = w4[c * 512 + t];
      int rr = c >> 1, p4 = c & 1;
      wz[rr][4 * p4] = v.x; wz[rr][4 * p4 + 1] = v.y;
      wz[rr][4 * p4 + 2] = v.z; wz[rr][4 * p4 + 3] = v.w;
    }
  }
  uint32_t we[16];                     // 16
  {
    const uint4* w4 = (const uint4*)wep_g;
    #pragma unroll
    for (int c = 0; c < 4; ++c) {
      uint4 v = w4[c * 512 + t];
      we[4 * c] = v.x; we[4 * c + 1] = v.y; we[4 * c + 2] = v.z; we[4 * c + 3] = v.w;
    }
  }
  #pragma unroll
  for (int rr = 0; rr < 3; ++rr) {
    #pragma unroll
    for (int i = 0; i < REG_P; ++i) asm volatile("" : "+v"(wrg[rr][i]));
    #pragma unroll
    for (int i = 0; i < 8; ++i)    asm volatile("" : "+v"(wz[rr][i]));
  }
  #pragma unroll
  for (int i = 0; i < 16; ++i) asm volatile("" : "+v"(we[i]));
  const float bhn = b_hh[512 + r];

  // ---- LDS (~158.9 KB) ----
  __shared__ uint32_t lwh[512 * LDSTR];          // 155,648 B
  __shared__ __align__(16) f16 hf[2][264];       // padded: half1 at f16 136 (R20 fix)
  __shared__ float encp[512];
  __shared__ uint32_t zu[16];

  {
    const uint4* src = (const uint4*)(whl_g + (size_t)t * LDSTR);
    uint4* dst = (uint4*)(lwh + (size_t)t * LDSTR);
    #pragma unroll
    for (int j = 0; j < LDSTR / 4; ++j) dst[j] = src[j];
  }

  const int hwidx = r + ((r >> 7) << 3);   // padded write index for row r
  float hm = 0.0f;
  if (!q) {
    hm = first ? 0.0f : hws[b * 256 + r];
    hf[0][hwidx] = (f16)hm;
  }
  __syncthreads();   // once, outside the loop

  // ---- stream prefetch for t=0 ----
  float pf_g0 = 0.0f, pf_g1 = 0.0f, pf_g2 = 0.0f;
  if (!q) {
    const f16* gp0 = gix + (size_t)b * 768;
    pf_g0 = (float)gp0[r]; pf_g1 = (float)gp0[r + 256]; pf_g2 = (float)gp0[r + 512];
  }
  float pf_zm = 0.0f, pf_zl = 0.0f, pf_ep = 0.0f;
  if (t < 32) {
    const f16* zp = zx + (size_t)b * 64;
    pf_zm = (float)zp[t]; pf_zl = (float)zp[32 + t];
    pf_ep = eps[((size_t)t0 * NB + b) * 32 + t];
  }

  const int s = t >> 6;                       // wave id (phase-A k-slice)
  const int abase = 4 * s + (s >= 4 ? 1 : 0); // padded quad base of slice s
  const int bq = q ? 17 : 0;                  // padded quad base of this k-half
  const uint32_t* myl = lwh + (size_t)t * LDSTR;
  const uint4* whs4 = (const uint4*)whs;

  // ---- preload stream chunks 0..2 for step 0 ----
  uint4 sa0, sa1, sa2, sb0, sb1, sb2, sc0, sc1, sc2;
  ISS(sa0, sa1, sa2, 0)
  ISS(sb0, sb1, sb2, 1)
  ISS(sc0, sc1, sc2, 2)

  for (int tl = 0; tl < Tlen; ++tl) {
    const int cur = tl & 1, nxt = cur ^ 1;
    const uint4* hu4 = (const uint4*)&hf[cur][0];

    // ---- phase A: encoder partials (wave-uniform h slice s) ----
    float ep_ = 0.0f;
    #pragma unroll
    for (int p4 = 0; p4 < 4; ++p4) {
      uint4 u4 = hu4[abase + p4];
      ep_ = dot2u(we[4 * p4],     u4.x, ep_);
      ep_ = dot2u(we[4 * p4 + 1], u4.y, ep_);
      ep_ = dot2u(we[4 * p4 + 2], u4.z, ep_);
      ep_ = dot2u(we[4 * p4 + 3], u4.w, ep_);
    }
    encp[t] = ep_;
    __syncthreads();  // b1

    // ---- phase B: z (32 threads) || gh (all threads, own k-half) ----
    if (t < 32) {
      float mu = pf_zm, lv = pf_zl;
      #pragma unroll
      for (int ss = 0; ss < 8; ++ss) {
        mu += encp[ss * 64 + t];
        lv += encp[ss * 64 + 32 + t];
      }
      float z = mu + pf_ep * exp2f(0.72134752f * lv);   // mu + eps*exp(0.5*lv)
      ((f16*)zu)[t] = (f16)z;
    }
    float g0 = 0.0f, g1 = 0.0f, g2 = 0.0f;
    // quads 0..2: register weights
    #pragma unroll
    for (int g4 = 0; g4 < 3; ++g4) {
      uint4 u4 = hu4[bq + g4];
      g0 = dot2u(wrg[0][4 * g4],     u4.x, g0);
      g1 = dot2u(wrg[1][4 * g4],     u4.x, g1);
      g2 = dot2u(wrg[2][4 * g4],     u4.x, g2);
      g0 = dot2u(wrg[0][4 * g4 + 1], u4.y, g0);
      g1 = dot2u(wrg[1][4 * g4 + 1], u4.y, g1);
      g2 = dot2u(wrg[2][4 * g4 + 1], u4.y, g2);
      g0 = dot2u(wrg[0][4 * g4 + 2], u4.z, g0);
      g1 = dot2u(wrg[1][4 * g4 + 2], u4.z, g1);
      g2 = dot2u(wrg[2][4 * g4 + 2], u4.z, g2);
      g0 = dot2u(wrg[0][4 * g4 + 3], u4.w, g0);
      g1 = dot2u(wrg[1][4 * g4 + 3], u4.w, g1);
      g2 = dot2u(wrg[2][4 * g4 + 3], u4.w, g2);
    }
    // depth-3 stream pipeline interleaved with LDS quads
    CONS(sa0, sa1, sa2, bq + 9)   ISS(sa0, sa1, sa2, 3)
    LQ(0)
    CONS(sb0, sb1, sb2, bq + 10)  ISS(sb0, sb1, sb2, 4)
    LQ(1)
    CONS(sc0, sc1, sc2, bq + 11)  ISS(sc0, sc1, sc2, 5)
    LQ(2)
    CONS(sa0, sa1, sa2, bq + 12)  ISS(sa0, sa1, sa2, 6)
    LQ(3)
    CONS(sb0, sb1, sb2, bq + 13)
    LQ(4)
    CONS(sc0, sc1, sc2, bq + 14)
    LQ(5)
    CONS(sa0, sa1, sa2, bq + 15)
    __syncthreads();  // b2  (zu visible)

    // ---- phase C: gi_z (own 8 z-pairs), pair-reduce, gates (even lanes) ----
    float q0 = 0.0f, q1 = 0.0f, q2 = 0.0f;
    #pragma unroll
    for (int p = 0; p < 8; ++p) {
      uint32_t u = zu[q * 8 + p];    // broadcast reads
      q0 = dot2u(wz[0][p], u, q0);
      q1 = dot2u(wz[1][p], u, q1);
      q2 = dot2u(wz[2][p], u, q2);
    }
    g0 += __shfl_xor(g0, 1); g1 += __shfl_xor(g1, 1); g2 += __shfl_xor(g2, 1);
    q0 += __shfl_xor(q0, 1); q1 += __shfl_xor(q1, 1); q2 += __shfl_xor(q2, 1);
    if (!q) {
      float rg = sigm(pf_g0 + g0 + q0);
      float uu = sigm(pf_g1 + g1 + q1);
      float n  = tanh_f(pf_g2 + q2 + rg * (g2 + bhn));
      hm = (1.0f - uu) * n + uu * hm;
      hf[nxt][hwidx] = (f16)hm;
    }

    // ---- issue stream chunks 0..2 for NEXT step ----
    ISS(sa0, sa1, sa2, 0)
    ISS(sb0, sb1, sb2, 1)
    ISS(sc0, sc1, sc2, 2)

    // ---- prefetch activation streams for tl+1 ----
    int tn = (tl + 1 < Tlen) ? tl + 1 : tl;
    if (!q) {
      const f16* gp = gix + ((size_t)tn * NB + b) * 768;
      pf_g0 = (float)gp[r]; pf_g1 = (float)gp[r + 256]; pf_g2 = (float)gp[r + 512];
    }
    if (t < 32) {
      const f16* zp = zx + ((size_t)tn * NB + b) * 64;
      pf_zm = (float)zp[t]; pf_zl = (float)zp[32 + t];
      pf_ep = eps[((size_t)(t0 + tn) * NB + b) * 32 + t];
    }
    __syncthreads();  // b3  (h_new visible)
  }

  if (!q) {
    if (last) out[b * 256 + r] = hm;
    else      hws[b * 256 + r] = hm;
  }
}

extern "C" void kernel_launch(void* const* d_in, const int* in_sizes, int n_in,
                              void* d_out, int out_size, void* d_ws, size_t ws_size,
                              hipStream_t stream) {
  const float* x    = (const float*)d_in[0];
  const float* eps  = (const float*)d_in[1];
  const float* emW  = (const float*)d_in[2];
  const float* emb  = (const float*)d_in[3];
  const float* esW  = (const float*)d_in[4];
  const float* esb  = (const float*)d_in[5];
  const float* W_ih = (const float*)d_in[10];
  const float* W_hh = (const float*)d_in[11];
  const float* b_ih = (const float*)d_in[12];
  const float* b_hh = (const float*)d_in[13];
  float* out = (float*)d_out;

  // workspace layout (16B-aligned regions)
  const size_t o_whr = 262144;                  // hws: 256 KB
  const size_t o_whl = o_whr + 73728;           // whr: 9*512*16
  const size_t o_whs = o_whl + 155648;          // whl: 76*512*4
  const size_t o_whz = o_whs + 172032;          // whs: 21*512*16
  const size_t o_wep = o_whz + 49152;           // whz: 6*512*16
  const size_t o_gix = o_wep + 32768;           // wep: 4*512*16  -> 745,472
  int Tc = TSEQ;
  while (Tc > 8 && o_gix + (size_t)Tc * NB * (768 + 64) * 2 > ws_size) Tc >>= 1;

  float*    hws   = (float*)d_ws;
  uint32_t* whr   = (uint32_t*)((char*)d_ws + o_whr);
  uint32_t* whl_g = (uint32_t*)((char*)d_ws + o_whl);
  uint32_t* whs   = (uint32_t*)((char*)d_ws + o_whs);
  uint32_t* whz   = (uint32_t*)((char*)d_ws + o_whz);
  uint32_t* wep   = (uint32_t*)((char*)d_ws + o_wep);
  f16*      gix   = (f16*)((char*)d_ws + o_gix);
  f16*      zx    = gix + (size_t)Tc * NB * 768;

  vrnn_pack<<<dim3(1), dim3(512), 0, stream>>>(W_hh, W_ih, emW, esW,
                                               whr, whl_g, whs, whz, wep);

  int nch = TSEQ / Tc;
  int TT  = Tc < 64 ? Tc : 64;
  int nTT = Tc / TT;

  for (int c = 0; c < nch; ++c) {
    vrnn_pre<<<dim3(NB * nTT), dim3(256), 0, stream>>>(
        x, W_ih, b_ih, b_hh, emW, emb, esW, esb, gix, zx, c * Tc, TT, nTT);
    vrnn_rec<<<dim3(NB), dim3(512), 0, stream>>>(
        gix, zx, eps, whr, whl_g, whs, whz, wep, b_hh, hws, out,
        c * Tc, Tc, c == 0 ? 1 : 0, c == nch - 1 ? 1 : 0);
  }
}